// Round 2
// baseline (783.828 us; speedup 1.0000x reference)
//
#include <hip/hip_runtime.h>

#define TT   256
#define INH  28
#define HH   64
#define OUTN 10

// tanh(x) = 1 - 2/(e^{2x}+1), clamped so e^{2x} can't overflow.
// |err| ~1e-7 vs libm tanh — fine for fp32 validation.
__device__ __forceinline__ float fast_tanh(float x) {
    float cx = fminf(fmaxf(x, -15.0f), 15.0f);
    float e2 = __expf(2.0f * cx);
    return 1.0f - 2.0f * __builtin_amdgcn_rcpf(e2 + 1.0f);
}

// One wave (64 lanes) owns 2 batch rows for the entire T loop, both RNN
// layers and the final FC. lane = hidden unit j. Weight row j of every
// matrix lives in that lane's VGPRs (220 regs). h-state round-trips LDS
// wave-synchronously (barrier-free kernel). h[k] is consumed as
// uniform-address ds_read_b128 broadcasts (conflict-free).
__global__ __launch_bounds__(256, 2)
void rnn2_fused(const float* __restrict__ x,
                const float* __restrict__ Wih0, const float* __restrict__ Whh0,
                const float* __restrict__ bih0, const float* __restrict__ bhh0,
                const float* __restrict__ Wih1, const float* __restrict__ Whh1,
                const float* __restrict__ bih1, const float* __restrict__ bhh1,
                const float* __restrict__ Wfc,  const float* __restrict__ bfc,
                float* __restrict__ out)
{
    __shared__ float h0s[8][HH];          // [rowslot][unit]
    __shared__ float h1s[8][HH];

    const int tid  = threadIdx.x;
    const int lane = tid & 63;
    const int wave = __builtin_amdgcn_readfirstlane(tid >> 6);

    // ---- per-lane weight rows in VGPRs (loaded once, 220 regs) ----
    float wih0[INH];
#pragma unroll
    for (int k = 0; k < INH; ++k) wih0[k] = Wih0[lane * INH + k];
    float whh0[HH];
#pragma unroll
    for (int k = 0; k < HH; ++k) whh0[k] = Whh0[lane * HH + k];
    float wih1[HH];
#pragma unroll
    for (int k = 0; k < HH; ++k) wih1[k] = Wih1[lane * HH + k];
    float whh1[HH];
#pragma unroll
    for (int k = 0; k < HH; ++k) whh1[k] = Whh1[lane * HH + k];

    const float bias0 = bih0[lane] + bhh0[lane];
    const float bias1 = bih1[lane] + bhh1[lane];

    const int slot0 = wave * 2 + 0;
    const int slot1 = wave * 2 + 1;
    // batch rows (wave-uniform scalars -> x addresses take the SGPR path)
    const int b0 = __builtin_amdgcn_readfirstlane((int)blockIdx.x * 8 + wave * 2);
    const int b1 = b0 + 1;

    // zero h state (wave-private rows; wave-synchronous)
    h0s[slot0][lane] = 0.0f; h0s[slot1][lane] = 0.0f;
    h1s[slot0][lane] = 0.0f; h1s[slot1][lane] = 0.0f;

    const float4* xq0 = (const float4*)(x + (size_t)b0 * (TT * INH)); // 7 float4 / step
    const float4* xq1 = (const float4*)(x + (size_t)b1 * (TT * INH));

    const float4* h0q0 = (const float4*)h0s[slot0];
    const float4* h0q1 = (const float4*)h0s[slot1];
    const float4* h1q0 = (const float4*)h1s[slot0];
    const float4* h1q1 = (const float4*)h1s[slot1];

#pragma unroll 1
    for (int t = 0; t < TT; ++t) {
        const float4* xr0 = xq0 + t * 7;
        const float4* xr1 = xq1 + t * 7;

        // ---- layer 0: p = bias0 + x·Wih0^T + h0·Whh0^T ----
        float pa0 = bias0, pb0 = 0.0f, pa1 = bias0, pb1 = 0.0f;
#pragma unroll
        for (int i = 0; i < 7; ++i) {               // x-proj (uniform-addr loads)
            float4 a = xr0[i], b = xr1[i];
            pa0 = fmaf(a.x, wih0[4*i+0], pa0); pa1 = fmaf(b.x, wih0[4*i+0], pa1);
            pb0 = fmaf(a.y, wih0[4*i+1], pb0); pb1 = fmaf(b.y, wih0[4*i+1], pb1);
            pa0 = fmaf(a.z, wih0[4*i+2], pa0); pa1 = fmaf(b.z, wih0[4*i+2], pa1);
            pb0 = fmaf(a.w, wih0[4*i+3], pb0); pb1 = fmaf(b.w, wih0[4*i+3], pb1);
        }
#pragma unroll
        for (int kk = 0; kk < 16; ++kk) {           // recurrence, h0 broadcast
            float4 a = h0q0[kk], b = h0q1[kk];
            pa0 = fmaf(a.x, whh0[4*kk+0], pa0); pa1 = fmaf(b.x, whh0[4*kk+0], pa1);
            pb0 = fmaf(a.y, whh0[4*kk+1], pb0); pb1 = fmaf(b.y, whh0[4*kk+1], pb1);
            pa0 = fmaf(a.z, whh0[4*kk+2], pa0); pa1 = fmaf(b.z, whh0[4*kk+2], pa1);
            pb0 = fmaf(a.w, whh0[4*kk+3], pb0); pb1 = fmaf(b.w, whh0[4*kk+3], pb1);
        }
        float nh00 = fast_tanh(pa0 + pb0);
        float nh01 = fast_tanh(pa1 + pb1);
        h0s[slot0][lane] = nh00;                    // wave-synchronous publish
        h0s[slot1][lane] = nh01;

        // ---- layer 1: q = bias1 + h0new·Wih1^T + h1old·Whh1^T ----
        // (two separate 16-iter loops: halves live float4 temps vs fused)
        float qa0 = bias1, qb0 = 0.0f, qa1 = bias1, qb1 = 0.0f;
#pragma unroll
        for (int kk = 0; kk < 16; ++kk) {
            float4 a = h0q0[kk], b = h0q1[kk];      // new h0 (after lgkmcnt)
            qa0 = fmaf(a.x, wih1[4*kk+0], qa0); qa1 = fmaf(b.x, wih1[4*kk+0], qa1);
            qb0 = fmaf(a.y, wih1[4*kk+1], qb0); qb1 = fmaf(b.y, wih1[4*kk+1], qb1);
            qa0 = fmaf(a.z, wih1[4*kk+2], qa0); qa1 = fmaf(b.z, wih1[4*kk+2], qa1);
            qb0 = fmaf(a.w, wih1[4*kk+3], qb0); qb1 = fmaf(b.w, wih1[4*kk+3], qb1);
        }
#pragma unroll
        for (int kk = 0; kk < 16; ++kk) {
            float4 c = h1q0[kk], d = h1q1[kk];      // old h1
            qa0 = fmaf(c.x, whh1[4*kk+0], qa0); qa1 = fmaf(d.x, whh1[4*kk+0], qa1);
            qb0 = fmaf(c.y, whh1[4*kk+1], qb0); qb1 = fmaf(d.y, whh1[4*kk+1], qb1);
            qa0 = fmaf(c.z, whh1[4*kk+2], qa0); qa1 = fmaf(d.z, whh1[4*kk+2], qa1);
            qb0 = fmaf(c.w, whh1[4*kk+3], qb0); qb1 = fmaf(d.w, whh1[4*kk+3], qb1);
        }
        float nh10 = fast_tanh(qa0 + qb0);
        float nh11 = fast_tanh(qa1 + qb1);
        h1s[slot0][lane] = nh10;
        h1s[slot1][lane] = nh11;
    }

    // ---- FC on last h1 (runs once; only lanes < OUTN produce output) ----
    if (lane < OUTN) {
        const float4* wrow = (const float4*)(Wfc + lane * HH);
        float acc0 = bfc[lane];
        float acc1 = acc0;
#pragma unroll
        for (int kk = 0; kk < 16; ++kk) {
            float4 w = wrow[kk];
            float4 a = h1q0[kk], b = h1q1[kk];
            acc0 = fmaf(a.x, w.x, acc0); acc1 = fmaf(b.x, w.x, acc1);
            acc0 = fmaf(a.y, w.y, acc0); acc1 = fmaf(b.y, w.y, acc1);
            acc0 = fmaf(a.z, w.z, acc0); acc1 = fmaf(b.z, w.z, acc1);
            acc0 = fmaf(a.w, w.w, acc0); acc1 = fmaf(b.w, w.w, acc1);
        }
        out[(size_t)b0 * OUTN + lane] = acc0;
        out[(size_t)b1 * OUTN + lane] = acc1;
    }
}

extern "C" void kernel_launch(void* const* d_in, const int* in_sizes, int n_in,
                              void* d_out, int out_size, void* d_ws, size_t ws_size,
                              hipStream_t stream) {
    const float* x    = (const float*)d_in[0];
    const float* Wih0 = (const float*)d_in[1];
    const float* Whh0 = (const float*)d_in[2];
    const float* bih0 = (const float*)d_in[3];
    const float* bhh0 = (const float*)d_in[4];
    const float* Wih1 = (const float*)d_in[5];
    const float* Whh1 = (const float*)d_in[6];
    const float* bih1 = (const float*)d_in[7];
    const float* bhh1 = (const float*)d_in[8];
    const float* Wfc  = (const float*)d_in[9];
    const float* bfc  = (const float*)d_in[10];
    float* out = (float*)d_out;

    // 4096 rows / (4 waves * 2 rows) = 512 blocks -> 2048 waves = 2/SIMD machine-wide
    rnn2_fused<<<512, 256, 0, stream>>>(x, Wih0, Whh0, bih0, bhh0,
                                        Wih1, Whh1, bih1, bhh1, Wfc, bfc, out);
}